// Round 11
// baseline (18.358 us; speedup 1.0000x reference)
//
#include <hip/hip_runtime.h>

// BilinearSparseRouting — collapsed form (dots = softmax(const) = 1/32 exactly):
//   S[b] (4x4) = sum_j cp_mat[b,j] @ wc[j]
//   out[b,i]   = (1/32) * S[b] @ wn[i]
//
// R11 = R10 with ONE change: cp loads are PLAIN (nontemporal dropped).
// Completes the {wc-hoist} x {nt} 2x2 matrix:
//   (no-hoist,no-nt)=17.9  (no-hoist,nt)=16.7  (hoist,nt)=16.8  (hoist,no-nt)=?
// Discriminates "nt helps the pure stream (L2-allocation avoidance)" vs
// "nt was only protecting in-loop wc (now redundant with the hoist)" vs
// "nt throttles the read path". wc stays hoisted into registers.

#define BATCH 256
#define NIN   4096
#define NOUT  32

constexpr int THREADS = 1024;
constexpr int VPT     = 4;                      // f32x4 per thread per iter
constexpr int POS     = NIN * 4;                // 16384 f32x4 positions / batch
constexpr int ITERS   = POS / (THREADS * VPT);  // 4
constexpr int WAVES   = THREADS / 64;           // 16

typedef __attribute__((ext_vector_type(4))) float f32x4;

template<int K>
__device__ __forceinline__ f32x4 quad_bcast(f32x4 x) {
    // VALU-pipe quad broadcast: v_mov_b32_dpp quad_perm:[K,K,K,K]
    constexpr int ctrl = K * 0x55;              // K|(K<<2)|(K<<4)|(K<<6)
    f32x4 r;
#pragma unroll
    for (int d = 0; d < 4; ++d)
        r[d] = __int_as_float(
            __builtin_amdgcn_mov_dpp(__float_as_int(x[d]), ctrl, 0xF, 0xF, true));
    return r;
}

__global__ __launch_bounds__(THREADS)
void caps_fused(const float* __restrict__ cp,
                const float* __restrict__ wc,
                const float* __restrict__ wn,
                float* __restrict__ out) {
    const int b    = blockIdx.x;
    const int t    = threadIdx.x;
    const int lane = t & 63;
    const int wave = t >> 6;

    const f32x4* cp4 = (const f32x4*)cp + (size_t)b * POS;
    const f32x4* wc4 = (const f32x4*)wc;

    // ---- hoist: all wc rows for this thread, loaded once up front ----
    f32x4 wpre[ITERS][VPT];
#pragma unroll
    for (int it = 0; it < ITERS; ++it)
#pragma unroll
        for (int v = 0; v < VPT; ++v)
            wpre[it][v] = wc4[it * (THREADS * VPT) + v * THREADS + t];

    f32x4 acc = {0.f, 0.f, 0.f, 0.f};   // row r=t&3 of S, partial

#pragma unroll
    for (int it = 0; it < ITERS; ++it) {
        f32x4 a[VPT];
#pragma unroll
        for (int v = 0; v < VPT; ++v) {
            const int p = it * (THREADS * VPT) + v * THREADS + t;
            a[v] = cp4[p];                       // plain load (A/B vs R10's nt)
        }
#pragma unroll
        for (int v = 0; v < VPT; ++v) {
            const f32x4 w0 = quad_bcast<0>(wpre[it][v]);
            const f32x4 w1 = quad_bcast<1>(wpre[it][v]);
            const f32x4 w2 = quad_bcast<2>(wpre[it][v]);
            const f32x4 w3 = quad_bcast<3>(wpre[it][v]);
            // acc[c] += sum_k a[k] * W[k][c]
            acc += a[v][0] * w0;
            acc += a[v][1] * w1;
            acc += a[v][2] * w2;
            acc += a[v][3] * w3;
        }
    }

    // Sum across lanes with equal (lane&3): butterfly over masks 4,8,16,32.
#pragma unroll
    for (int m = 4; m <= 32; m <<= 1) {
#pragma unroll
        for (int c = 0; c < 4; ++c)
            acc[c] += __shfl_xor(acc[c], m, 64);
    }

    __shared__ f32x4 red[WAVES][4];
    __shared__ float S[16];
    if (lane < 4) red[wave][lane] = acc;   // lane == row r
    __syncthreads();

    if (t < 16) {                           // t = r*4 + c
        float v = 0.f;
#pragma unroll
        for (int w2 = 0; w2 < WAVES; ++w2) v += red[w2][t >> 2][t & 3];
        S[t] = v * (1.0f / 32.0f);
    }
    __syncthreads();

    // Epilogue: out[b,i,r,0..3] = S[r,:] @ wn[i][:,0..3], 128 threads x f32x4
    if (t < NOUT * 4) {
        const int i = t >> 2;
        const int r = t & 3;
        const f32x4* wn4 = (const f32x4*)(wn + i * 16);
        const f32x4 w0 = wn4[0], w1 = wn4[1], w2 = wn4[2], w3 = wn4[3];
        const float s0 = S[r * 4 + 0], s1 = S[r * 4 + 1];
        const float s2 = S[r * 4 + 2], s3 = S[r * 4 + 3];
        f32x4 o;
        o[0] = s0 * w0[0] + s1 * w1[0] + s2 * w2[0] + s3 * w3[0];
        o[1] = s0 * w0[1] + s1 * w1[1] + s2 * w2[1] + s3 * w3[1];
        o[2] = s0 * w0[2] + s1 * w1[2] + s2 * w2[2] + s3 * w3[2];
        o[3] = s0 * w0[3] + s1 * w1[3] + s2 * w2[3] + s3 * w3[3];
        ((f32x4*)(out + (size_t)b * NOUT * 16))[t] = o;
    }
}

extern "C" void kernel_launch(void* const* d_in, const int* in_sizes, int n_in,
                              void* d_out, int out_size, void* d_ws, size_t ws_size,
                              hipStream_t stream) {
    const float* cp = (const float*)d_in[0];   // (256,4096,16)
    const float* wc = (const float*)d_in[1];   // (1,1,4096,4,4)
    const float* wn = (const float*)d_in[2];   // (32,4,4)
    float* out = (float*)d_out;                // (256,1,1,32,16)

    caps_fused<<<BATCH, THREADS, 0, stream>>>(cp, wc, wn, out);
}

// Round 12
// 17.973 us; speedup vs baseline: 1.0214x; 1.0214x over previous
//
#include <hip/hip_runtime.h>

// BilinearSparseRouting — collapsed form (dots = softmax(const) = 1/32 exactly):
//   S[b] (4x4) = sum_j cp_mat[b,j] @ wc[j]
//   out[b,i]   = (1/32) * S[b] @ wn[i]
//
// R12 = R10 (wc hoisted, cp nontemporal) + per-block cp-stream rotation.
// Clean retest of the HBM channel-aliasing theory WITHOUT R8's confound:
// R8 rotated the shared wc walk too (desync killed wc L2 reuse); here wc is
// register-hoisted in the prologue so rotation touches only the private cp
// stream. Rotation = +b*64 f32x4 (b*1 KiB), mod the 256 KiB chunk: a
// bijection, preserves p&3 (row/quad structure intact for the DPP bcast),
// and gives the 256 CUs distinct low-address offsets at every instant.

#define BATCH 256
#define NIN   4096
#define NOUT  32

constexpr int THREADS = 1024;
constexpr int VPT     = 4;                      // f32x4 per thread per iter
constexpr int POS     = NIN * 4;                // 16384 f32x4 positions / batch
constexpr int ITERS   = POS / (THREADS * VPT);  // 4
constexpr int WAVES   = THREADS / 64;           // 16

typedef __attribute__((ext_vector_type(4))) float f32x4;

template<int K>
__device__ __forceinline__ f32x4 quad_bcast(f32x4 x) {
    // VALU-pipe quad broadcast: v_mov_b32_dpp quad_perm:[K,K,K,K]
    constexpr int ctrl = K * 0x55;              // K|(K<<2)|(K<<4)|(K<<6)
    f32x4 r;
#pragma unroll
    for (int d = 0; d < 4; ++d)
        r[d] = __int_as_float(
            __builtin_amdgcn_mov_dpp(__float_as_int(x[d]), ctrl, 0xF, 0xF, true));
    return r;
}

__global__ __launch_bounds__(THREADS)
void caps_fused(const float* __restrict__ cp,
                const float* __restrict__ wc,
                const float* __restrict__ wn,
                float* __restrict__ out) {
    const int b    = blockIdx.x;
    const int t    = threadIdx.x;
    const int lane = t & 63;
    const int wave = t >> 6;

    const f32x4* cp4 = (const f32x4*)cp + (size_t)b * POS;
    const f32x4* wc4 = (const f32x4*)wc;

    // per-block rotation: +b*64 f32x4 positions (1 KiB per block), mod chunk.
    // b*64 ≡ 0 (mod 4) -> p&3 (row-in-quad) unchanged; bijection on the chunk.
    const int rot0 = (b * 64) & (POS - 1);

    // ---- prologue: hoist all wc rows (rotated indices to match cp) ----
    f32x4 wpre[ITERS][VPT];
#pragma unroll
    for (int it = 0; it < ITERS; ++it)
#pragma unroll
        for (int v = 0; v < VPT; ++v) {
            const int p = (it * (THREADS * VPT) + v * THREADS + t + rot0) & (POS - 1);
            wpre[it][v] = wc4[p];
        }

    f32x4 acc = {0.f, 0.f, 0.f, 0.f};   // row r=t&3 of S, partial

#pragma unroll
    for (int it = 0; it < ITERS; ++it) {
        f32x4 a[VPT];
#pragma unroll
        for (int v = 0; v < VPT; ++v) {
            const int p = (it * (THREADS * VPT) + v * THREADS + t + rot0) & (POS - 1);
            a[v] = __builtin_nontemporal_load(cp4 + p);  // pure HBM stream
        }
#pragma unroll
        for (int v = 0; v < VPT; ++v) {
            const f32x4 w0 = quad_bcast<0>(wpre[it][v]);
            const f32x4 w1 = quad_bcast<1>(wpre[it][v]);
            const f32x4 w2 = quad_bcast<2>(wpre[it][v]);
            const f32x4 w3 = quad_bcast<3>(wpre[it][v]);
            // acc[c] += sum_k a[k] * W[k][c]
            acc += a[v][0] * w0;
            acc += a[v][1] * w1;
            acc += a[v][2] * w2;
            acc += a[v][3] * w3;
        }
    }

    // Sum across lanes with equal (lane&3): butterfly over masks 4,8,16,32.
#pragma unroll
    for (int m = 4; m <= 32; m <<= 1) {
#pragma unroll
        for (int c = 0; c < 4; ++c)
            acc[c] += __shfl_xor(acc[c], m, 64);
    }

    __shared__ f32x4 red[WAVES][4];
    __shared__ float S[16];
    if (lane < 4) red[wave][lane] = acc;   // lane == row r (rot0 ≡ 0 mod 4)
    __syncthreads();

    if (t < 16) {                           // t = r*4 + c
        float v = 0.f;
#pragma unroll
        for (int w2 = 0; w2 < WAVES; ++w2) v += red[w2][t >> 2][t & 3];
        S[t] = v * (1.0f / 32.0f);
    }
    __syncthreads();

    // Epilogue: out[b,i,r,0..3] = S[r,:] @ wn[i][:,0..3], 128 threads x f32x4
    if (t < NOUT * 4) {
        const int i = t >> 2;
        const int r = t & 3;
        const f32x4* wn4 = (const f32x4*)(wn + i * 16);
        const f32x4 w0 = wn4[0], w1 = wn4[1], w2 = wn4[2], w3 = wn4[3];
        const float s0 = S[r * 4 + 0], s1 = S[r * 4 + 1];
        const float s2 = S[r * 4 + 2], s3 = S[r * 4 + 3];
        f32x4 o;
        o[0] = s0 * w0[0] + s1 * w1[0] + s2 * w2[0] + s3 * w3[0];
        o[1] = s0 * w0[1] + s1 * w1[1] + s2 * w2[1] + s3 * w3[1];
        o[2] = s0 * w0[2] + s1 * w1[2] + s2 * w2[2] + s3 * w3[2];
        o[3] = s0 * w0[3] + s1 * w1[3] + s2 * w2[3] + s3 * w3[3];
        ((f32x4*)(out + (size_t)b * NOUT * 16))[t] = o;
    }
}

extern "C" void kernel_launch(void* const* d_in, const int* in_sizes, int n_in,
                              void* d_out, int out_size, void* d_ws, size_t ws_size,
                              hipStream_t stream) {
    const float* cp = (const float*)d_in[0];   // (256,4096,16)
    const float* wc = (const float*)d_in[1];   // (1,1,4096,4,4)
    const float* wn = (const float*)d_in[2];   // (32,4,4)
    float* out = (float*)d_out;                // (256,1,1,32,16)

    caps_fused<<<BATCH, THREADS, 0, stream>>>(cp, wc, wn, out);
}

// Round 13
// 16.759 us; speedup vs baseline: 1.0954x; 1.0724x over previous
//
#include <hip/hip_runtime.h>

// BilinearSparseRouting — collapsed form (dots = softmax(const) = 1/32 exactly):
//   S[b] (4x4) = sum_j cp_mat[b,j] @ wc[j]
//   out[b,i]   = (1/32) * S[b] @ wn[i]
//
// R13 = revert to R9, the measured-best config (16.73 us):
//  - 256 blocks x 1024 threads, one block per CU, single fused kernel
//  - lane-contiguous global_load_dwordx4 for cp AND wc (1 KiB/instr)
//  - cp loads NONTEMPORAL (zero-reuse 64 MiB stream; keeps wc L2-resident:
//    the one confirmed L2-interaction win, +1.5 us)
//  - wc loads in-loop, cached (hoist measured null R10/R11)
//  - W-row quad-broadcast via VALU DPP (DS/VALU both fine; global scalar bad)
//  - sequential lockstep walk (rotation regressed twice, R8/R12)

#define BATCH 256
#define NIN   4096
#define NOUT  32

constexpr int THREADS = 1024;
constexpr int VPT     = 4;                      // f32x4 per thread per iter
constexpr int POS     = NIN * 4;                // 16384 f32x4 positions / batch
constexpr int ITERS   = POS / (THREADS * VPT);  // 4
constexpr int WAVES   = THREADS / 64;           // 16

typedef __attribute__((ext_vector_type(4))) float f32x4;

template<int K>
__device__ __forceinline__ f32x4 quad_bcast(f32x4 x) {
    // VALU-pipe quad broadcast: v_mov_b32_dpp quad_perm:[K,K,K,K]
    constexpr int ctrl = K * 0x55;              // K|(K<<2)|(K<<4)|(K<<6)
    f32x4 r;
#pragma unroll
    for (int d = 0; d < 4; ++d)
        r[d] = __int_as_float(
            __builtin_amdgcn_mov_dpp(__float_as_int(x[d]), ctrl, 0xF, 0xF, true));
    return r;
}

__global__ __launch_bounds__(THREADS)
void caps_fused(const float* __restrict__ cp,
                const float* __restrict__ wc,
                const float* __restrict__ wn,
                float* __restrict__ out) {
    const int b    = blockIdx.x;
    const int t    = threadIdx.x;
    const int lane = t & 63;
    const int wave = t >> 6;

    const f32x4* cp4 = (const f32x4*)cp + (size_t)b * POS;
    const f32x4* wc4 = (const f32x4*)wc;

    f32x4 acc = {0.f, 0.f, 0.f, 0.f};   // row r=t&3 of S, partial

#pragma unroll
    for (int it = 0; it < ITERS; ++it) {
        f32x4 a[VPT], w[VPT];
#pragma unroll
        for (int v = 0; v < VPT; ++v) {
            const int p = it * (THREADS * VPT) + v * THREADS + t;
            a[v] = __builtin_nontemporal_load(cp4 + p);  // streaming, L2-bypass
            w[v] = wc4[p];                                // cached (shared tile)
        }
#pragma unroll
        for (int v = 0; v < VPT; ++v) {
            const f32x4 w0 = quad_bcast<0>(w[v]);
            const f32x4 w1 = quad_bcast<1>(w[v]);
            const f32x4 w2 = quad_bcast<2>(w[v]);
            const f32x4 w3 = quad_bcast<3>(w[v]);
            // acc[c] += sum_k a[k] * W[k][c]
            acc += a[v][0] * w0;
            acc += a[v][1] * w1;
            acc += a[v][2] * w2;
            acc += a[v][3] * w3;
        }
    }

    // Sum across lanes with equal (lane&3): butterfly over masks 4,8,16,32.
#pragma unroll
    for (int m = 4; m <= 32; m <<= 1) {
#pragma unroll
        for (int c = 0; c < 4; ++c)
            acc[c] += __shfl_xor(acc[c], m, 64);
    }

    __shared__ f32x4 red[WAVES][4];
    __shared__ float S[16];
    if (lane < 4) red[wave][lane] = acc;   // lane == row r
    __syncthreads();

    if (t < 16) {                           // t = r*4 + c
        float v = 0.f;
#pragma unroll
        for (int w2 = 0; w2 < WAVES; ++w2) v += red[w2][t >> 2][t & 3];
        S[t] = v * (1.0f / 32.0f);
    }
    __syncthreads();

    // Epilogue: out[b,i,r,0..3] = S[r,:] @ wn[i][:,0..3], 128 threads x f32x4
    if (t < NOUT * 4) {
        const int i = t >> 2;
        const int r = t & 3;
        const f32x4* wn4 = (const f32x4*)(wn + i * 16);
        const f32x4 w0 = wn4[0], w1 = wn4[1], w2 = wn4[2], w3 = wn4[3];
        const float s0 = S[r * 4 + 0], s1 = S[r * 4 + 1];
        const float s2 = S[r * 4 + 2], s3 = S[r * 4 + 3];
        f32x4 o;
        o[0] = s0 * w0[0] + s1 * w1[0] + s2 * w2[0] + s3 * w3[0];
        o[1] = s0 * w0[1] + s1 * w1[1] + s2 * w2[1] + s3 * w3[1];
        o[2] = s0 * w0[2] + s1 * w1[2] + s2 * w2[2] + s3 * w3[2];
        o[3] = s0 * w0[3] + s1 * w1[3] + s2 * w2[3] + s3 * w3[3];
        ((f32x4*)(out + (size_t)b * NOUT * 16))[t] = o;
    }
}

extern "C" void kernel_launch(void* const* d_in, const int* in_sizes, int n_in,
                              void* d_out, int out_size, void* d_ws, size_t ws_size,
                              hipStream_t stream) {
    const float* cp = (const float*)d_in[0];   // (256,4096,16)
    const float* wc = (const float*)d_in[1];   // (1,1,4096,4,4)
    const float* wn = (const float*)d_in[2];   // (32,4,4)
    float* out = (float*)d_out;                // (256,1,1,32,16)

    caps_fused<<<BATCH, THREADS, 0, stream>>>(cp, wc, wn, out);
}